// Round 1
// baseline (666.822 us; speedup 1.0000x reference)
//
#include <hip/hip_runtime.h>
#include <math.h>

#define NBLK    2048
#define NTHR    256
#define ITERS   8          // items per slot per block
#define NNODE   17
#define HH      32
#define BTOT    131072

// per half-wave (32 lanes) slot scratch; all float4-read fields 16B aligned
struct __align__(16) SlotMem {
    float Ah[NNODE][20];   // [0,340)  A_hat rows, padded to 20 (80B, 16B-aligned rows)
    float dinv[20];        // [340,360)
    float xd[20];          // [360,380) x_str * dinv
    float ex[32];          // [380,412) agg1 / agg2 exchange
    float c[56];           // [412,468) head combined input (PASS2)
    float z[64];           // [468,532) head hidden exchange (PASS2)
};                         // 532 floats = 2128 B

template<int PASS>
__global__ __launch_bounds__(NTHR) void gcn_kernel(
    const float* __restrict__ x_str, const float* __restrict__ x_raw,
    const float* __restrict__ adj,   const float* __restrict__ x_cov,
    const float* __restrict__ age,
    const float* __restrict__ W1, const float* __restrict__ b1,
    const float* __restrict__ W2, const float* __restrict__ b2,
    const float* __restrict__ gamma, const float* __restrict__ beta,
    const float* __restrict__ Wr1, const float* __restrict__ br1,
    const float* __restrict__ Wr2, const float* __restrict__ br2,
    const float* __restrict__ Wr3, const float* __restrict__ br3,
    float* __restrict__ gstat,   // ws: [0..16] sum, [17..33] sumsq
    float* __restrict__ out)
{
    __shared__ SlotMem slots[8];
    __shared__ __align__(16) float hw[(PASS == 2) ? 5504 : 1];   // Wr1(pairs)|br1|Wr2
    __shared__ float s17[(PASS == 2) ? 18 : 1];                  // scale/17 per node + C
    __shared__ float statb[(PASS == 1) ? 4 * 34 : 1];

    const int tid  = threadIdx.x;
    const int slot = tid >> 5;
    const int lane = tid & 31;
    SlotMem& sm = slots[slot];

    // per-lane weights (lane = hidden channel o)
    const float W1o = W1[lane];
    const float b1o = b1[lane];
    const float b2o = b2[lane];
    float W2col[HH];
    #pragma unroll
    for (int k = 0; k < HH; ++k) W2col[k] = W2[k * HH + lane];

    float Wr3o = 0.f, br2o = 0.f, br3v = 0.f;
    if constexpr (PASS == 2) {
        Wr3o = Wr3[lane];
        br2o = br2[lane];
        br3v = br3[0];
        // stage head weights into LDS; Wr1 packed as float2 (j, j+32) pairs
        for (int t = tid; t < 5504; t += NTHR) {
            float v;
            if (t < 3392) {
                int i = t >> 6, r = t & 63;
                v = Wr1[i * 64 + ((r & 1) << 5) + (r >> 1)];
            } else if (t < 3456) {
                v = br1[t - 3392];
            } else {
                v = Wr2[t - 3456];
            }
            hw[t] = v;
        }
        if (tid == 0) {
            const float invBH = 1.0f / ((float)BTOT * (float)HH);
            float Cs = 0.f;
            #pragma unroll
            for (int n = 0; n < NNODE; ++n) {
                float mean = gstat[n] * invBH;
                float var  = gstat[NNODE + n] * invBH - mean * mean;
                float sc   = gamma[n] * rsqrtf(var + 1e-5f);
                s17[n] = sc * (1.0f / (float)NNODE);
                Cs += beta[n] - mean * sc;
            }
            s17[NNODE] = Cs * (1.0f / (float)NNODE);
        }
        __syncthreads();
    }

    float psum[NNODE], psq[NNODE];
    if constexpr (PASS == 1) {
        #pragma unroll
        for (int n = 0; n < NNODE; ++n) { psum[n] = 0.f; psq[n] = 0.f; }
    }

    const int base = blockIdx.x * (ITERS * 8);

    for (int it = 0; it < ITERS; ++it) {
        const int item = base + it * 8 + slot;
        const size_t aoff = (size_t)item * (NNODE * NNODE);

        // ---- stage A_hat = adj + I into LDS (coalesced: 2x contiguous slabs/wave)
        for (int k = lane; k < NNODE * NNODE; k += 32) {
            int n = k / NNODE;
            int m = k - n * NNODE;
            float v = adj[aoff + k];
            if (n == m) v += 1.0f;
            sm.Ah[n][m] = v;
        }
        float xs = 0.f;
        if (lane < NNODE) xs = x_str[(size_t)item * NNODE + lane];
        // ---- degrees -> d^{-1/2}; xd = dinv*x   (lanes 0..16; same-wave LDS RAW ok)
        if (lane < NNODE) {
            float d = 0.f;
            #pragma unroll
            for (int m = 0; m < NNODE; ++m) d += sm.Ah[lane][m];
            float di = (d > 0.f) ? rsqrtf(d) : 0.f;
            sm.dinv[lane] = di;
            sm.xd[lane]   = di * xs;
        }
        // ---- agg1[n] = dinv[n] * sum_m Ah[n][m]*xd[m]
        if (lane < NNODE) {
            float a = 0.f;
            #pragma unroll
            for (int m = 0; m < NNODE; ++m) a += sm.Ah[lane][m] * sm.xd[m];
            sm.ex[lane] = a * sm.dinv[lane];
        }
        // ---- h1d[m] = dinv[m] * elu(agg1[m]*W1[o] + b1[o])   (per-lane regs)
        float h1d[NNODE];
        #pragma unroll
        for (int m = 0; m < NNODE; ++m) {
            float a = sm.ex[m] * W1o + b1o;
            float h = (a > 0.f) ? a : (__expf(a) - 1.0f);
            h1d[m] = sm.dinv[m] * h;
        }

        float emb = 0.f;
        // ---- layer-2 GCN rows
        for (int n = 0; n < NNODE; ++n) {
            const float4* rowv = reinterpret_cast<const float4*>(sm.Ah[n]);
            float4 r0 = rowv[0], r1 = rowv[1], r2 = rowv[2], r3 = rowv[3];
            float acc;
            acc  = r0.x*h1d[0]  + r0.y*h1d[1]  + r0.z*h1d[2]  + r0.w*h1d[3];
            acc += r1.x*h1d[4]  + r1.y*h1d[5]  + r1.z*h1d[6]  + r1.w*h1d[7];
            acc += r2.x*h1d[8]  + r2.y*h1d[9]  + r2.z*h1d[10] + r2.w*h1d[11];
            acc += r3.x*h1d[12] + r3.y*h1d[13] + r3.z*h1d[14] + r3.w*h1d[15];
            acc += sm.Ah[n][16] * h1d[16];
            float a2 = acc * sm.dinv[n];           // agg2[n][o]
            sm.ex[lane] = a2;                      // exchange across lanes (same wave)
            const float4* exv = reinterpret_cast<const float4*>(sm.ex);
            float hacc = b2o;
            #pragma unroll
            for (int q = 0; q < 8; ++q) {
                float4 e = exv[q];
                hacc += e.x * W2col[4*q]   + e.y * W2col[4*q+1]
                      + e.z * W2col[4*q+2] + e.w * W2col[4*q+3];
            }
            float h2 = (hacc > 0.f) ? hacc : (__expf(hacc) - 1.0f);
            if constexpr (PASS == 1) {
                psum[n] += h2;
                psq[n]  += h2 * h2;
            } else {
                emb += s17[n] * h2;
            }
        }

        if constexpr (PASS == 2) {
            emb += s17[NNODE];
            // ---- build combined[53] = [emb(32), x_raw(17), x_cov(3), age(1)]
            sm.c[lane] = emb;
            if (lane < NNODE) sm.c[HH + lane] = x_raw[(size_t)item * NNODE + lane];
            if (lane < 3)     sm.c[49 + lane] = x_cov[(size_t)item * 3 + lane];
            if (lane == 0)    sm.c[52] = age[item];
            // ---- head layer 1: j = lane and lane+32
            float a1 = hw[3392 + lane];
            float a2h = hw[3392 + 32 + lane];
            for (int i = 0; i < 52; i += 4) {
                float4 cv = *reinterpret_cast<const float4*>(&sm.c[i]);
                #pragma unroll
                for (int u = 0; u < 4; ++u) {
                    float cu = (&cv.x)[u];
                    float2 w = *reinterpret_cast<const float2*>(&hw[(i + u) * 64 + lane * 2]);
                    a1  += cu * w.x;
                    a2h += cu * w.y;
                }
            }
            {
                float cu = sm.c[52];
                float2 w = *reinterpret_cast<const float2*>(&hw[52 * 64 + lane * 2]);
                a1 += cu * w.x; a2h += cu * w.y;
            }
            a1 = fmaxf(a1, 0.f); a2h = fmaxf(a2h, 0.f);
            sm.z[lane] = a1;
            sm.z[32 + lane] = a2h;
            // ---- head layer 2
            float acc = br2o;
            for (int i = 0; i < 64; i += 4) {
                float4 zv = *reinterpret_cast<const float4*>(&sm.z[i]);
                #pragma unroll
                for (int u = 0; u < 4; ++u)
                    acc += (&zv.x)[u] * hw[3456 + (i + u) * 32 + lane];
            }
            acc = fmaxf(acc, 0.f);
            // ---- head layer 3 + sigmoid (half-wave reduce)
            float v = acc * Wr3o;
            v += __shfl_xor(v, 16, 32);
            v += __shfl_xor(v, 8, 32);
            v += __shfl_xor(v, 4, 32);
            v += __shfl_xor(v, 2, 32);
            v += __shfl_xor(v, 1, 32);
            if (lane == 0) {
                float s = v + br3v;
                out[item] = 1.0f / (1.0f + __expf(-s));
            }
        }
    }

    if constexpr (PASS == 1) {
        // full-wave butterfly: every lane ends with wave totals
        #pragma unroll
        for (int n = 0; n < NNODE; ++n) {
            float a = psum[n], b = psq[n];
            #pragma unroll
            for (int m = 32; m >= 1; m >>= 1) {
                a += __shfl_xor(a, m, 64);
                b += __shfl_xor(b, m, 64);
            }
            psum[n] = a; psq[n] = b;
        }
        const int w = tid >> 6;
        if ((tid & 63) == 0) {
            #pragma unroll
            for (int n = 0; n < NNODE; ++n) {
                statb[w * 34 + n]          = psum[n];
                statb[w * 34 + NNODE + n]  = psq[n];
            }
        }
        __syncthreads();
        if (tid < 34) {
            float s = statb[tid] + statb[34 + tid] + statb[68 + tid] + statb[102 + tid];
            unsafeAtomicAdd(&gstat[tid], s);
        }
    }
}

extern "C" void kernel_launch(void* const* d_in, const int* in_sizes, int n_in,
                              void* d_out, int out_size, void* d_ws, size_t ws_size,
                              hipStream_t stream) {
    (void)in_sizes; (void)n_in; (void)out_size; (void)ws_size;
    const float* x_str = (const float*)d_in[0];
    const float* x_raw = (const float*)d_in[1];
    const float* adj   = (const float*)d_in[2];
    const float* x_cov = (const float*)d_in[3];
    const float* age   = (const float*)d_in[4];
    const float* W1    = (const float*)d_in[5];
    const float* b1    = (const float*)d_in[6];
    const float* W2    = (const float*)d_in[7];
    const float* b2    = (const float*)d_in[8];
    const float* gamma = (const float*)d_in[9];
    const float* beta  = (const float*)d_in[10];
    const float* Wr1   = (const float*)d_in[11];
    const float* br1   = (const float*)d_in[12];
    const float* Wr2   = (const float*)d_in[13];
    const float* br2   = (const float*)d_in[14];
    const float* Wr3   = (const float*)d_in[15];
    const float* br3   = (const float*)d_in[16];
    float* gstat = (float*)d_ws;
    float* out   = (float*)d_out;

    hipMemsetAsync(d_ws, 0, 34 * sizeof(float), stream);
    gcn_kernel<1><<<NBLK, NTHR, 0, stream>>>(x_str, x_raw, adj, x_cov, age,
        W1, b1, W2, b2, gamma, beta, Wr1, br1, Wr2, br2, Wr3, br3, gstat, out);
    gcn_kernel<2><<<NBLK, NTHR, 0, stream>>>(x_str, x_raw, adj, x_cov, age,
        W1, b1, W2, b2, gamma, beta, Wr1, br1, Wr2, br2, Wr3, br3, gstat, out);
}

// Round 2
// 516.919 us; speedup vs baseline: 1.2900x; 1.2900x over previous
//
#include <hip/hip_runtime.h>
#include <hip/hip_bf16.h>
#include <math.h>

#define NNODE   17
#define HH      32
#define BTOT    131072

__device__ __forceinline__ float blo(unsigned u){ return __uint_as_float(u << 16); }
__device__ __forceinline__ float bhi(unsigned u){ return __uint_as_float(u & 0xFFFF0000u); }

// ---------------------------------------------------------------- PASS 1
struct __align__(16) Slot1 {
    float Ah[NNODE][20];        // A_hat rows, padded to 20 (16B-aligned rows)
    float dinv[20];
    float xd[20];               // dinv * x_str
    float ag[20];               // agg1
    __hip_bfloat16 g[NNODE][32];// agg2 exchange (bf16), 64B rows, 16B-aligned
};

__global__ __launch_bounds__(256) void pass1_kernel(
    const float* __restrict__ x_str, const float* __restrict__ adj,
    const float* __restrict__ W1, const float* __restrict__ b1,
    const float* __restrict__ W2, const float* __restrict__ b2,
    __hip_bfloat16* __restrict__ h2g)
{
    __shared__ Slot1 slots[8];
    const int tid  = threadIdx.x;
    const int slot = tid >> 5;
    const int lane = tid & 31;
    Slot1& sm = slots[slot];

    const float W1o = W1[lane], b1o = b1[lane], b2o = b2[lane];
    float W2col[HH];
    #pragma unroll
    for (int k = 0; k < HH; ++k) W2col[k] = W2[k * HH + lane];

    const int base = blockIdx.x * 64;
    for (int it = 0; it < 8; ++it) {
        const int item = base + it * 8 + slot;
        const size_t aoff = (size_t)item * (NNODE * NNODE);

        // stage A_hat = adj + I (coalesced)
        for (int k = lane; k < NNODE * NNODE; k += 32) {
            int n = (k * 241) >> 12;        // k/17 for k<=288
            int m = k - n * NNODE;
            float v = adj[aoff + k];
            sm.Ah[n][m] = (n == m) ? v + 1.0f : v;
        }
        float xs = (lane < NNODE) ? x_str[(size_t)item * NNODE + lane] : 0.f;
        if (lane < NNODE) {
            float d = 0.f;
            #pragma unroll
            for (int m = 0; m < NNODE; ++m) d += sm.Ah[lane][m];
            float di = (d > 0.f) ? rsqrtf(d) : 0.f;
            sm.dinv[lane] = di;
            sm.xd[lane]   = di * xs;
        }
        if (lane < NNODE) {
            float a = 0.f;
            #pragma unroll
            for (int m = 0; m < NNODE; ++m) a += sm.Ah[lane][m] * sm.xd[m];
            sm.ag[lane] = a * sm.dinv[lane];
        }
        // h1d[m] = dinv[m] * elu(agg1[m]*W1[o] + b1[o])
        float h1d[NNODE];
        #pragma unroll
        for (int m = 0; m < NNODE; ++m) {
            float a = sm.ag[m] * W1o + b1o;
            float h = (a > 0.f) ? a : (__expf(a) - 1.0f);
            h1d[m] = sm.dinv[m] * h;
        }
        // phase A: all 17 agg2 rows -> LDS (bf16), independent chains
        for (int n = 0; n < NNODE; ++n) {
            const float4* rowv = reinterpret_cast<const float4*>(sm.Ah[n]);
            float4 r0 = rowv[0], r1 = rowv[1], r2 = rowv[2], r3 = rowv[3];
            float acc;
            acc  = r0.x*h1d[0]  + r0.y*h1d[1]  + r0.z*h1d[2]  + r0.w*h1d[3];
            acc += r1.x*h1d[4]  + r1.y*h1d[5]  + r1.z*h1d[6]  + r1.w*h1d[7];
            acc += r2.x*h1d[8]  + r2.y*h1d[9]  + r2.z*h1d[10] + r2.w*h1d[11];
            acc += r3.x*h1d[12] + r3.y*h1d[13] + r3.z*h1d[14] + r3.w*h1d[15];
            acc += sm.Ah[n][16] * h1d[16];
            sm.g[n][lane] = __float2bfloat16(acc * sm.dinv[n]);
        }
        // phase B: h2[n][o] = elu(agg2[n]·W2col + b2) ; store bf16 to global
        __hip_bfloat16* hp = h2g + (size_t)item * (NNODE * 32) + lane;
        for (int n = 0; n < NNODE; ++n) {
            const uint4* gp = reinterpret_cast<const uint4*>(sm.g[n]);
            float hacc = b2o;
            #pragma unroll
            for (int q = 0; q < 4; ++q) {
                uint4 u = gp[q];
                hacc += blo(u.x)*W2col[8*q+0] + bhi(u.x)*W2col[8*q+1]
                      + blo(u.y)*W2col[8*q+2] + bhi(u.y)*W2col[8*q+3]
                      + blo(u.z)*W2col[8*q+4] + bhi(u.z)*W2col[8*q+5]
                      + blo(u.w)*W2col[8*q+6] + bhi(u.w)*W2col[8*q+7];
            }
            float h2 = (hacc > 0.f) ? hacc : (__expf(hacc) - 1.0f);
            hp[n * 32] = __float2bfloat16(h2);
        }
    }
}

// ---------------------------------------------------------------- STATS
__global__ __launch_bounds__(576) void stats_kernel(
    const __hip_bfloat16* __restrict__ h2g, float* __restrict__ gstat)
{
    const int t = threadIdx.x;
    float s = 0.f, q = 0.f;
    if (t < 544) {
        for (int item = blockIdx.x; item < BTOT; item += gridDim.x) {
            float v = __bfloat162float(h2g[(size_t)item * 544 + t]);
            s += v; q += v * v;
        }
    }
    #pragma unroll
    for (int m = 16; m >= 1; m >>= 1) {
        s += __shfl_xor(s, m, 32);
        q += __shfl_xor(q, m, 32);
    }
    if (t < 544 && (t & 31) == 0) {
        int n = t >> 5;
        unsafeAtomicAdd(&gstat[n], s);
        unsafeAtomicAdd(&gstat[NNODE + n], q);
    }
}

// ---------------------------------------------------------------- PASS 2 (head)
struct __align__(16) Slot2 {
    float c[56];
    float z[64];
};

__global__ __launch_bounds__(256) void pass2_kernel(
    const __hip_bfloat16* __restrict__ h2g,
    const float* __restrict__ x_raw, const float* __restrict__ x_cov,
    const float* __restrict__ age,
    const float* __restrict__ gamma, const float* __restrict__ beta,
    const float* __restrict__ Wr1, const float* __restrict__ br1,
    const float* __restrict__ Wr2, const float* __restrict__ br2,
    const float* __restrict__ Wr3, const float* __restrict__ br3,
    const float* __restrict__ gstat, float* __restrict__ out)
{
    __shared__ Slot2 slots[8];
    __shared__ __align__(16) float hw[5504];   // Wr1(pairs)|br1|Wr2
    __shared__ float s17[18];

    const int tid  = threadIdx.x;
    const int slot = tid >> 5;
    const int lane = tid & 31;
    Slot2& sm = slots[slot];

    const float Wr3o = Wr3[lane];
    const float br2o = br2[lane];
    const float br3v = br3[0];

    for (int t = tid; t < 5504; t += 256) {
        float v;
        if (t < 3392) {
            int i = t >> 6, r = t & 63;
            v = Wr1[i * 64 + ((r & 1) << 5) + (r >> 1)];
        } else if (t < 3456) {
            v = br1[t - 3392];
        } else {
            v = Wr2[t - 3456];
        }
        hw[t] = v;
    }
    if (tid == 0) {
        const float invBH = 1.0f / ((float)BTOT * (float)HH);
        float Cs = 0.f;
        #pragma unroll
        for (int n = 0; n < NNODE; ++n) {
            float mean = gstat[n] * invBH;
            float var  = gstat[NNODE + n] * invBH - mean * mean;
            float sc   = gamma[n] * rsqrtf(var + 1e-5f);
            s17[n] = sc * (1.0f / (float)NNODE);
            Cs += beta[n] - mean * sc;
        }
        s17[NNODE] = Cs * (1.0f / (float)NNODE);
    }
    __syncthreads();

    const int base = blockIdx.x * 64;
    for (int it = 0; it < 8; ++it) {
        const int item = base + it * 8 + slot;

        // emb[o] = sum_n s17[n]*h2[n][o] + C
        const __hip_bfloat16* hp = h2g + (size_t)item * 544 + lane;
        float emb = s17[NNODE];
        #pragma unroll
        for (int n = 0; n < NNODE; ++n)
            emb += s17[n] * __bfloat162float(hp[n * 32]);

        sm.c[lane] = emb;
        if (lane < NNODE) sm.c[HH + lane] = x_raw[(size_t)item * NNODE + lane];
        if (lane < 3)     sm.c[49 + lane] = x_cov[(size_t)item * 3 + lane];
        if (lane == 0)    sm.c[52] = age[item];

        float a1  = hw[3392 + lane];
        float a2h = hw[3392 + 32 + lane];
        for (int i = 0; i < 52; i += 4) {
            float4 cv = *reinterpret_cast<const float4*>(&sm.c[i]);
            #pragma unroll
            for (int u = 0; u < 4; ++u) {
                float cu = (&cv.x)[u];
                float2 w = *reinterpret_cast<const float2*>(&hw[(i + u) * 64 + lane * 2]);
                a1  += cu * w.x;
                a2h += cu * w.y;
            }
        }
        {
            float cu = sm.c[52];
            float2 w = *reinterpret_cast<const float2*>(&hw[52 * 64 + lane * 2]);
            a1 += cu * w.x; a2h += cu * w.y;
        }
        a1 = fmaxf(a1, 0.f); a2h = fmaxf(a2h, 0.f);
        sm.z[lane] = a1;
        sm.z[32 + lane] = a2h;

        float acc = br2o;
        for (int i = 0; i < 64; i += 4) {
            float4 zv = *reinterpret_cast<const float4*>(&sm.z[i]);
            #pragma unroll
            for (int u = 0; u < 4; ++u)
                acc += (&zv.x)[u] * hw[3456 + (i + u) * 32 + lane];
        }
        acc = fmaxf(acc, 0.f);

        float v = acc * Wr3o;
        v += __shfl_xor(v, 16, 32);
        v += __shfl_xor(v, 8, 32);
        v += __shfl_xor(v, 4, 32);
        v += __shfl_xor(v, 2, 32);
        v += __shfl_xor(v, 1, 32);
        if (lane == 0)
            out[item] = 1.0f / (1.0f + __expf(-(v + br3v)));
    }
}

// ---------------------------------------------------------------- fallback (prev round, passing)
struct __align__(16) SlotMem {
    float Ah[NNODE][20];
    float dinv[20];
    float xd[20];
    float ex[32];
    float c[56];
    float z[64];
};

template<int PASS>
__global__ __launch_bounds__(256) void gcn_fb_kernel(
    const float* __restrict__ x_str, const float* __restrict__ x_raw,
    const float* __restrict__ adj,   const float* __restrict__ x_cov,
    const float* __restrict__ age,
    const float* __restrict__ W1, const float* __restrict__ b1,
    const float* __restrict__ W2, const float* __restrict__ b2,
    const float* __restrict__ gamma, const float* __restrict__ beta,
    const float* __restrict__ Wr1, const float* __restrict__ br1,
    const float* __restrict__ Wr2, const float* __restrict__ br2,
    const float* __restrict__ Wr3, const float* __restrict__ br3,
    float* __restrict__ gstat, float* __restrict__ out)
{
    __shared__ SlotMem slots[8];
    __shared__ __align__(16) float hw[(PASS == 2) ? 5504 : 1];
    __shared__ float s17[(PASS == 2) ? 18 : 1];
    __shared__ float statb[(PASS == 1) ? 4 * 34 : 1];

    const int tid  = threadIdx.x;
    const int slot = tid >> 5;
    const int lane = tid & 31;
    SlotMem& sm = slots[slot];

    const float W1o = W1[lane];
    const float b1o = b1[lane];
    const float b2o = b2[lane];
    float W2col[HH];
    #pragma unroll
    for (int k = 0; k < HH; ++k) W2col[k] = W2[k * HH + lane];

    float Wr3o = 0.f, br2o = 0.f, br3v = 0.f;
    if constexpr (PASS == 2) {
        Wr3o = Wr3[lane];
        br2o = br2[lane];
        br3v = br3[0];
        for (int t = tid; t < 5504; t += 256) {
            float v;
            if (t < 3392) {
                int i = t >> 6, r = t & 63;
                v = Wr1[i * 64 + ((r & 1) << 5) + (r >> 1)];
            } else if (t < 3456) {
                v = br1[t - 3392];
            } else {
                v = Wr2[t - 3456];
            }
            hw[t] = v;
        }
        if (tid == 0) {
            const float invBH = 1.0f / ((float)BTOT * (float)HH);
            float Cs = 0.f;
            #pragma unroll
            for (int n = 0; n < NNODE; ++n) {
                float mean = gstat[n] * invBH;
                float var  = gstat[NNODE + n] * invBH - mean * mean;
                float sc   = gamma[n] * rsqrtf(var + 1e-5f);
                s17[n] = sc * (1.0f / (float)NNODE);
                Cs += beta[n] - mean * sc;
            }
            s17[NNODE] = Cs * (1.0f / (float)NNODE);
        }
        __syncthreads();
    }

    float psum[NNODE], psq[NNODE];
    if constexpr (PASS == 1) {
        #pragma unroll
        for (int n = 0; n < NNODE; ++n) { psum[n] = 0.f; psq[n] = 0.f; }
    }

    const int base = blockIdx.x * 64;
    for (int it = 0; it < 8; ++it) {
        const int item = base + it * 8 + slot;
        const size_t aoff = (size_t)item * (NNODE * NNODE);

        for (int k = lane; k < NNODE * NNODE; k += 32) {
            int n = k / NNODE;
            int m = k - n * NNODE;
            float v = adj[aoff + k];
            if (n == m) v += 1.0f;
            sm.Ah[n][m] = v;
        }
        float xs = 0.f;
        if (lane < NNODE) xs = x_str[(size_t)item * NNODE + lane];
        if (lane < NNODE) {
            float d = 0.f;
            #pragma unroll
            for (int m = 0; m < NNODE; ++m) d += sm.Ah[lane][m];
            float di = (d > 0.f) ? rsqrtf(d) : 0.f;
            sm.dinv[lane] = di;
            sm.xd[lane]   = di * xs;
        }
        if (lane < NNODE) {
            float a = 0.f;
            #pragma unroll
            for (int m = 0; m < NNODE; ++m) a += sm.Ah[lane][m] * sm.xd[m];
            sm.ex[lane] = a * sm.dinv[lane];
        }
        float h1d[NNODE];
        #pragma unroll
        for (int m = 0; m < NNODE; ++m) {
            float a = sm.ex[m] * W1o + b1o;
            float h = (a > 0.f) ? a : (__expf(a) - 1.0f);
            h1d[m] = sm.dinv[m] * h;
        }

        float emb = 0.f;
        for (int n = 0; n < NNODE; ++n) {
            const float4* rowv = reinterpret_cast<const float4*>(sm.Ah[n]);
            float4 r0 = rowv[0], r1 = rowv[1], r2 = rowv[2], r3 = rowv[3];
            float acc;
            acc  = r0.x*h1d[0]  + r0.y*h1d[1]  + r0.z*h1d[2]  + r0.w*h1d[3];
            acc += r1.x*h1d[4]  + r1.y*h1d[5]  + r1.z*h1d[6]  + r1.w*h1d[7];
            acc += r2.x*h1d[8]  + r2.y*h1d[9]  + r2.z*h1d[10] + r2.w*h1d[11];
            acc += r3.x*h1d[12] + r3.y*h1d[13] + r3.z*h1d[14] + r3.w*h1d[15];
            acc += sm.Ah[n][16] * h1d[16];
            float a2 = acc * sm.dinv[n];
            sm.ex[lane] = a2;
            const float4* exv = reinterpret_cast<const float4*>(sm.ex);
            float hacc = b2o;
            #pragma unroll
            for (int q = 0; q < 8; ++q) {
                float4 e = exv[q];
                hacc += e.x * W2col[4*q]   + e.y * W2col[4*q+1]
                      + e.z * W2col[4*q+2] + e.w * W2col[4*q+3];
            }
            float h2 = (hacc > 0.f) ? hacc : (__expf(hacc) - 1.0f);
            if constexpr (PASS == 1) {
                psum[n] += h2;
                psq[n]  += h2 * h2;
            } else {
                emb += s17[n] * h2;
            }
        }

        if constexpr (PASS == 2) {
            emb += s17[NNODE];
            sm.c[lane] = emb;
            if (lane < NNODE) sm.c[HH + lane] = x_raw[(size_t)item * NNODE + lane];
            if (lane < 3)     sm.c[49 + lane] = x_cov[(size_t)item * 3 + lane];
            if (lane == 0)    sm.c[52] = age[item];
            float a1 = hw[3392 + lane];
            float a2h = hw[3392 + 32 + lane];
            for (int i = 0; i < 52; i += 4) {
                float4 cv = *reinterpret_cast<const float4*>(&sm.c[i]);
                #pragma unroll
                for (int u = 0; u < 4; ++u) {
                    float cu = (&cv.x)[u];
                    float2 w = *reinterpret_cast<const float2*>(&hw[(i + u) * 64 + lane * 2]);
                    a1  += cu * w.x;
                    a2h += cu * w.y;
                }
            }
            {
                float cu = sm.c[52];
                float2 w = *reinterpret_cast<const float2*>(&hw[52 * 64 + lane * 2]);
                a1 += cu * w.x; a2h += cu * w.y;
            }
            a1 = fmaxf(a1, 0.f); a2h = fmaxf(a2h, 0.f);
            sm.z[lane] = a1;
            sm.z[32 + lane] = a2h;
            float acc = br2o;
            for (int i = 0; i < 64; i += 4) {
                float4 zv = *reinterpret_cast<const float4*>(&sm.z[i]);
                #pragma unroll
                for (int u = 0; u < 4; ++u)
                    acc += (&zv.x)[u] * hw[3456 + (i + u) * 32 + lane];
            }
            acc = fmaxf(acc, 0.f);
            float v = acc * Wr3o;
            v += __shfl_xor(v, 16, 32);
            v += __shfl_xor(v, 8, 32);
            v += __shfl_xor(v, 4, 32);
            v += __shfl_xor(v, 2, 32);
            v += __shfl_xor(v, 1, 32);
            if (lane == 0) {
                float s = v + br3v;
                out[item] = 1.0f / (1.0f + __expf(-s));
            }
        }
    }

    if constexpr (PASS == 1) {
        #pragma unroll
        for (int n = 0; n < NNODE; ++n) {
            float a = psum[n], b = psq[n];
            #pragma unroll
            for (int m = 32; m >= 1; m >>= 1) {
                a += __shfl_xor(a, m, 64);
                b += __shfl_xor(b, m, 64);
            }
            psum[n] = a; psq[n] = b;
        }
        const int w = tid >> 6;
        if ((tid & 63) == 0) {
            #pragma unroll
            for (int n = 0; n < NNODE; ++n) {
                statb[w * 34 + n]         = psum[n];
                statb[w * 34 + NNODE + n] = psq[n];
            }
        }
        __syncthreads();
        if (tid < 34) {
            float s = statb[tid] + statb[34 + tid] + statb[68 + tid] + statb[102 + tid];
            unsafeAtomicAdd(&gstat[tid], s);
        }
    }
}

extern "C" void kernel_launch(void* const* d_in, const int* in_sizes, int n_in,
                              void* d_out, int out_size, void* d_ws, size_t ws_size,
                              hipStream_t stream) {
    (void)in_sizes; (void)n_in; (void)out_size;
    const float* x_str = (const float*)d_in[0];
    const float* x_raw = (const float*)d_in[1];
    const float* adj   = (const float*)d_in[2];
    const float* x_cov = (const float*)d_in[3];
    const float* age   = (const float*)d_in[4];
    const float* W1    = (const float*)d_in[5];
    const float* b1    = (const float*)d_in[6];
    const float* W2    = (const float*)d_in[7];
    const float* b2    = (const float*)d_in[8];
    const float* gamma = (const float*)d_in[9];
    const float* beta  = (const float*)d_in[10];
    const float* Wr1   = (const float*)d_in[11];
    const float* br1   = (const float*)d_in[12];
    const float* Wr2   = (const float*)d_in[13];
    const float* br2   = (const float*)d_in[14];
    const float* Wr3   = (const float*)d_in[15];
    const float* br3   = (const float*)d_in[16];
    float* gstat = (float*)d_ws;
    float* out   = (float*)d_out;

    const size_t need = 256 + (size_t)BTOT * 544 * 2;
    hipMemsetAsync(d_ws, 0, 34 * sizeof(float), stream);
    if (ws_size >= need) {
        __hip_bfloat16* h2g = (__hip_bfloat16*)((char*)d_ws + 256);
        pass1_kernel<<<2048, 256, 0, stream>>>(x_str, adj, W1, b1, W2, b2, h2g);
        stats_kernel<<<256, 576, 0, stream>>>(h2g, gstat);
        pass2_kernel<<<2048, 256, 0, stream>>>(h2g, x_raw, x_cov, age, gamma, beta,
            Wr1, br1, Wr2, br2, Wr3, br3, gstat, out);
    } else {
        gcn_fb_kernel<1><<<2048, 256, 0, stream>>>(x_str, x_raw, adj, x_cov, age,
            W1, b1, W2, b2, gamma, beta, Wr1, br1, Wr2, br2, Wr3, br3, gstat, out);
        gcn_fb_kernel<2><<<2048, 256, 0, stream>>>(x_str, x_raw, adj, x_cov, age,
            W1, b1, W2, b2, gamma, beta, Wr1, br1, Wr2, br2, Wr3, br3, gstat, out);
    }
}